// Round 7
// baseline (928.117 us; speedup 1.0000x reference)
//
#include <hip/hip_runtime.h>
#include <cstddef>

// DecoderLayer: T=4, B=4, N=512, D=512, F=2048, H=8, head_dim=64
// I/O: float32. Round 15: round 14's A-only-LDS diet (6 LDS ops/wave-K-step)
// + the missing piece: B fragments are PREFETCHED INTO REGISTERS one K-step
// ahead (round 14 loaded them at point of use -> ~200cyc L2 stall every
// iteration, all pipes idle). Same MFMA stream -> bit-identical numerics.
#define T_STEPS 4
#define BN 2048
#define N_TOK 512
#define D_DIM 512
#define F_DIM 2048

#define MODE_SPK 0
#define MODE_SPK_ADD 1
#define MODE_OUT 2

#define FLAG_CAP (2u * 1024u * 1024u)

typedef float f32x4 __attribute__((ext_vector_type(4)));
typedef short s16x8 __attribute__((ext_vector_type(8)));
typedef unsigned int u32;

__device__ __forceinline__ float bf2f(unsigned short u) {
  unsigned int x = ((unsigned int)u) << 16;
  float f;
  __builtin_memcpy(&f, &x, 4);
  return f;
}
__device__ __forceinline__ unsigned short f2bf(float f) {
  unsigned int x;
  __builtin_memcpy(&x, &f, 4);
  x += 0x7fffu + ((x >> 16) & 1u);  // RNE
  return (unsigned short)(x >> 16);
}

// ---------------------------------------------------------------------------
// Weight preprocessing: for each W [K,N] f32 produce bf16 split transposed
// planes WhT, WmT [N,K] with w = wh + wm + r, |r| <= 2^-16|w|.
// ---------------------------------------------------------------------------
__global__ __launch_bounds__(256) void wsplit_k(
    const float* w0, const float* w1, const float* w2, const float* w3,
    const float* w4, const float* w5, const float* w6, const float* w7,
    const float* w8, const float* w9,
    unsigned short* __restrict__ WhT, unsigned short* __restrict__ WmT) {
  __shared__ float T[32][33];
  const int tile = blockIdx.x;
  const float* w;
  int Kd, Nd, lt;
  size_t off;
  if (tile < 2048) {
    const float* ws[8] = {w0, w1, w2, w3, w4, w5, w6, w7};
    int m = tile >> 8;
    lt = tile & 255; Kd = 512; Nd = 512; off = (size_t)m * 262144; w = ws[m];
  } else if (tile < 3072) {
    lt = tile - 2048; Kd = 512; Nd = 2048; off = 2097152; w = w8;
  } else {
    lt = tile - 3072; Kd = 2048; Nd = 512; off = 3145728; w = w9;
  }
  const int tilesK = Kd / 32;
  const int tk = lt % tilesK, tn = lt / tilesK;
  {
    int r = threadIdx.x >> 3, c4 = (threadIdx.x & 7) * 4;
    float4 v = *reinterpret_cast<const float4*>(
        w + (size_t)(tk * 32 + r) * Nd + tn * 32 + c4);
    T[r][c4 + 0] = v.x; T[r][c4 + 1] = v.y;
    T[r][c4 + 2] = v.z; T[r][c4 + 3] = v.w;
  }
  __syncthreads();
  {
    int n = threadIdx.x >> 3, k4 = (threadIdx.x & 7) * 4;
    float wv[4];
#pragma unroll
    for (int j = 0; j < 4; ++j) wv[j] = T[k4 + j][n];
    size_t ob = off + (size_t)(tn * 32 + n) * Kd + tk * 32 + k4;
    ushort4 h, m2;
    unsigned short* hp = &h.x; unsigned short* mp = &m2.x;
#pragma unroll
    for (int j = 0; j < 4; ++j) {
      unsigned short hh = f2bf(wv[j]);
      float r = wv[j] - bf2f(hh);   // exact
      hp[j] = hh; mp[j] = f2bf(r);
    }
    *reinterpret_cast<ushort4*>(WhT + ob) = h;
    *reinterpret_cast<ushort4*>(WmT + ob) = m2;
  }
}

__global__ void zero_k(unsigned int* c) {
  if (threadIdx.x < 8) c[threadIdx.x] = 0u;
}

// ---------------------------------------------------------------------------
// A-operand split: av = A1 (f32) [+ bf2f(A2)]; Ah = bf16(av), Am = bf16(av-Ah).
// ---------------------------------------------------------------------------
__global__ __launch_bounds__(256) void asplit_k(
    const float* __restrict__ A1, const unsigned short* __restrict__ A2,
    unsigned short* __restrict__ Ah, unsigned short* __restrict__ Am) {
  const size_t base = ((size_t)blockIdx.x * 256 + threadIdx.x) * 8;
  float4 f0 = *reinterpret_cast<const float4*>(A1 + base);
  float4 f1 = *reinterpret_cast<const float4*>(A1 + base + 4);
  float av[8] = {f0.x, f0.y, f0.z, f0.w, f1.x, f1.y, f1.z, f1.w};
  if (A2 != nullptr) {
    uint4 s = *reinterpret_cast<const uint4*>(A2 + base);
    const unsigned int* pu = &s.x;
#pragma unroll
    for (int j = 0; j < 4; ++j) {
      av[2 * j]     += bf2f((unsigned short)(pu[j] & 0xffffu));
      av[2 * j + 1] += bf2f((unsigned short)(pu[j] >> 16));
    }
  }
  unsigned int ph[4], pm[4];
#pragma unroll
  for (int j = 0; j < 4; ++j) {
    unsigned short h0 = f2bf(av[2 * j]);
    unsigned short h1 = f2bf(av[2 * j + 1]);
    float r0 = av[2 * j] - bf2f(h0);
    float r1 = av[2 * j + 1] - bf2f(h1);
    ph[j] = (unsigned int)h0 | ((unsigned int)h1 << 16);
    pm[j] = (unsigned int)f2bf(r0) | ((unsigned int)f2bf(r1) << 16);
  }
  uint4 vh; vh.x = ph[0]; vh.y = ph[1]; vh.z = ph[2]; vh.w = ph[3];
  uint4 vm; vm.x = pm[0]; vm.y = pm[1]; vm.z = pm[2]; vm.w = pm[3];
  *reinterpret_cast<uint4*>(Ah + base) = vh;
  *reinterpret_cast<uint4*>(Am + base) = vm;
}

// ---------------------------------------------------------------------------
// Split-precision bf16-MFMA GEMM + LIF over T + uncertainty flagging.
// Block tile 64 rows (16 bn x 4 t) x 64 cols; 4 waves, wave tile 32x32 =
// 2x2 mfma 16x16x32. A planes staged in LDS (80 B row stride); B fragments
// loaded from global (L2/L1-hot) with REGISTER DOUBLE-BUFFER prefetch one
// K-step ahead so the L2 latency hides under the MFMA body + barrier.
// acc_hi += ah*bh; acc_mid += ah*bm (+ am*bh if Am); acc_abs += |ah|*|bh|.
// u = f64(hi+mid)+bias, E = errC*abs; flagged -> f64 recompute (fix_k).
// Grid: (nxb*ngemm, BN/16), block 256.
// ---------------------------------------------------------------------------
__global__ __launch_bounds__(256, 4) void gemm_ns(
    const unsigned short* __restrict__ Ah, const unsigned short* __restrict__ Am,
    const unsigned short* __restrict__ WhTa, const unsigned short* __restrict__ WhTb,
    const unsigned short* __restrict__ WhTc,
    const unsigned short* __restrict__ WmTa, const unsigned short* __restrict__ WmTb,
    const unsigned short* __restrict__ WmTc,
    const float* __restrict__ ba, const float* __restrict__ bb,
    const float* __restrict__ bc,
    const unsigned short* Sprev, const float* __restrict__ Xres,
    const unsigned short* __restrict__ S12,
    void* outa, void* outb, void* outc,
    unsigned int* __restrict__ cnt, unsigned int* __restrict__ flags,
    int N, int K, int nxb, int mode, float errC) {
  // LDS 10240 B main loop: Ah@0, Am@5120 (64 rows x 32 k bf16, 80 B stride).
  // Epilogue overlay: UXS f32[16][128]@0 (8 KB), UXA @8192 (8 KB) -> 16384.
  __shared__ char smem[16384];

  const int sel = (int)blockIdx.x / nxb;
  const int nb = (int)blockIdx.x - sel * nxb;
  const unsigned short* WhT = sel == 0 ? WhTa : (sel == 1 ? WhTb : WhTc);
  const unsigned short* WmT = sel == 0 ? WmTa : (sel == 1 ? WmTb : WmTc);
  const float* bias = sel == 0 ? ba : (sel == 1 ? bb : bc);
  void* outv = sel == 0 ? outa : (sel == 1 ? outb : outc);
  const bool hasAm = (Am != nullptr);

  const int tid = threadIdx.x;
  const int lane = tid & 63;
  const int wave = tid >> 6;
  const int wr = wave >> 1, wcq = wave & 1;
  const int lm = lane & 15, quad = lane >> 4;
  const int n0 = nb * 64;
  const int bn0 = (int)blockIdx.y * 16;

  // staging roles: srow = A tile-row (0..63), skg = k-octet
  const int srow = tid >> 2;
  const int skg = tid & 3;
  const size_t aoff_row = (size_t)((srow >> 4) * BN + bn0 + (srow & 15)) * K;

  // B fragment base pointers (per-lane, direct global)
  const unsigned short* bp0 = WhT + (size_t)(n0 + wcq * 32 + lm) * K + quad * 8;
  const unsigned short* bp1 = WhT + (size_t)(n0 + wcq * 32 + 16 + lm) * K + quad * 8;
  const unsigned short* mp0 = WmT + (size_t)(n0 + wcq * 32 + lm) * K + quad * 8;
  const unsigned short* mp1 = WmT + (size_t)(n0 + wcq * 32 + 16 + lm) * K + quad * 8;

  f32x4 accH[2][2], accM[2][2], accA[2][2];
#pragma unroll
  for (int i = 0; i < 2; ++i)
#pragma unroll
    for (int j = 0; j < 2; ++j) {
      accH[i][j] = (f32x4){0.f, 0.f, 0.f, 0.f};
      accM[i][j] = (f32x4){0.f, 0.f, 0.f, 0.f};
      accA[i][j] = (f32x4){0.f, 0.f, 0.f, 0.f};
    }

  // prefetch registers (A staging + B fragment double-buffer)
  uint4 pah = {0, 0, 0, 0}, pam = {0, 0, 0, 0};
  s16x8 cbH0, cbH1, cbM0, cbM1;   // current B frags
  s16x8 nbH0, nbH1, nbM0, nbM1;   // next B frags

#define LOAD_TILE(K0)                                                        \
  do {                                                                       \
    pah = *reinterpret_cast<const uint4*>(Ah + aoff_row + (K0) + skg * 8);   \
    if (hasAm)                                                               \
      pam = *reinterpret_cast<const uint4*>(Am + aoff_row + (K0) + skg * 8); \
  } while (0)

#define LOAD_B(dst0, dst1, dst2, dst3, K0)                                   \
  do {                                                                       \
    dst0 = *reinterpret_cast<const s16x8*>(bp0 + (K0));                      \
    dst1 = *reinterpret_cast<const s16x8*>(bp1 + (K0));                      \
    dst2 = *reinterpret_cast<const s16x8*>(mp0 + (K0));                      \
    dst3 = *reinterpret_cast<const s16x8*>(mp1 + (K0));                      \
  } while (0)

#define STAGE()                                                              \
  do {                                                                       \
    *reinterpret_cast<uint4*>(smem + 0 + srow * 80 + skg * 16) = pah;        \
    if (hasAm)                                                               \
      *reinterpret_cast<uint4*>(smem + 5120 + srow * 80 + skg * 16) = pam;   \
  } while (0)

  const int aoff0 = (wr * 32 + lm) * 80 + quad * 16;
  const int aoff1 = aoff0 + 16 * 80;

  LOAD_TILE(0);
  LOAD_B(cbH0, cbH1, cbM0, cbM1, 0);
  for (int k0 = 0; k0 < K; k0 += 32) {
    STAGE();
    __syncthreads();
    if (k0 + 32 < K) {
      LOAD_TILE(k0 + 32);
      LOAD_B(nbH0, nbH1, nbM0, nbM1, k0 + 32);
    }
    s16x8 aH0 = *reinterpret_cast<const s16x8*>(smem + 0 + aoff0);
    s16x8 aH1 = *reinterpret_cast<const s16x8*>(smem + 0 + aoff1);
    s16x8 aA0 = aH0 & (short)0x7FFF;
    s16x8 aA1 = aH1 & (short)0x7FFF;
    s16x8 bA0 = cbH0 & (short)0x7FFF;
    s16x8 bA1 = cbH1 & (short)0x7FFF;
    accH[0][0] = __builtin_amdgcn_mfma_f32_16x16x32_bf16(aH0, cbH0, accH[0][0], 0, 0, 0);
    accH[0][1] = __builtin_amdgcn_mfma_f32_16x16x32_bf16(aH0, cbH1, accH[0][1], 0, 0, 0);
    accH[1][0] = __builtin_amdgcn_mfma_f32_16x16x32_bf16(aH1, cbH0, accH[1][0], 0, 0, 0);
    accH[1][1] = __builtin_amdgcn_mfma_f32_16x16x32_bf16(aH1, cbH1, accH[1][1], 0, 0, 0);
    accM[0][0] = __builtin_amdgcn_mfma_f32_16x16x32_bf16(aH0, cbM0, accM[0][0], 0, 0, 0);
    accM[0][1] = __builtin_amdgcn_mfma_f32_16x16x32_bf16(aH0, cbM1, accM[0][1], 0, 0, 0);
    accM[1][0] = __builtin_amdgcn_mfma_f32_16x16x32_bf16(aH1, cbM0, accM[1][0], 0, 0, 0);
    accM[1][1] = __builtin_amdgcn_mfma_f32_16x16x32_bf16(aH1, cbM1, accM[1][1], 0, 0, 0);
    if (hasAm) {
      s16x8 aM0 = *reinterpret_cast<const s16x8*>(smem + 5120 + aoff0);
      s16x8 aM1 = *reinterpret_cast<const s16x8*>(smem + 5120 + aoff1);
      accM[0][0] = __builtin_amdgcn_mfma_f32_16x16x32_bf16(aM0, cbH0, accM[0][0], 0, 0, 0);
      accM[0][1] = __builtin_amdgcn_mfma_f32_16x16x32_bf16(aM0, cbH1, accM[0][1], 0, 0, 0);
      accM[1][0] = __builtin_amdgcn_mfma_f32_16x16x32_bf16(aM1, cbH0, accM[1][0], 0, 0, 0);
      accM[1][1] = __builtin_amdgcn_mfma_f32_16x16x32_bf16(aM1, cbH1, accM[1][1], 0, 0, 0);
    }
    accA[0][0] = __builtin_amdgcn_mfma_f32_16x16x32_bf16(aA0, bA0, accA[0][0], 0, 0, 0);
    accA[0][1] = __builtin_amdgcn_mfma_f32_16x16x32_bf16(aA0, bA1, accA[0][1], 0, 0, 0);
    accA[1][0] = __builtin_amdgcn_mfma_f32_16x16x32_bf16(aA1, bA0, accA[1][0], 0, 0, 0);
    accA[1][1] = __builtin_amdgcn_mfma_f32_16x16x32_bf16(aA1, bA1, accA[1][1], 0, 0, 0);
    __syncthreads();
    cbH0 = nbH0; cbH1 = nbH1; cbM0 = nbM0; cbM1 = nbM1;
  }
#undef LOAD_TILE
#undef LOAD_B
#undef STAGE

  // ---- epilogue ----
  float* UXS = (float*)smem;
  float* UXA = (float*)(smem + 8192);
  if (wr == 1) {
#pragma unroll
    for (int mt = 0; mt < 2; ++mt)
#pragma unroll
      for (int nt = 0; nt < 2; ++nt)
#pragma unroll
        for (int j = 0; j < 4; ++j) {
          int i = mt * 8 + nt * 4 + j;
          UXS[i * 128 + wcq * 64 + lane] = accH[mt][nt][j] + accM[mt][nt][j];
          UXA[i * 128 + wcq * 64 + lane] = accA[mt][nt][j];
        }
  }
  __syncthreads();
  if (wr == 0) {
#pragma unroll
    for (int nt = 0; nt < 2; ++nt) {
      const int col = n0 + wcq * 32 + nt * 16 + lm;
      const double bb2 = (double)bias[col];
#pragma unroll
      for (int j = 0; j < 4; ++j) {
        const int bn = bn0 + quad * 4 + j;
        float sv[4], Ev[4];
        sv[0] = accH[0][nt][j] + accM[0][nt][j];
        sv[1] = accH[1][nt][j] + accM[1][nt][j];
        sv[2] = UXS[(0 * 8 + nt * 4 + j) * 128 + wcq * 64 + lane];
        sv[3] = UXS[(1 * 8 + nt * 4 + j) * 128 + wcq * 64 + lane];
        Ev[0] = errC * accA[0][nt][j];
        Ev[1] = errC * accA[1][nt][j];
        Ev[2] = errC * UXA[(0 * 8 + nt * 4 + j) * 128 + wcq * 64 + lane];
        Ev[3] = errC * UXA[(1 * 8 + nt * 4 + j) * 128 + wcq * 64 + lane];
        double v = 0.0;
        float errv = 0.f;
        bool flg = false;
        unsigned int spbits = 0;
#pragma unroll
        for (int t = 0; t < T_STEPS; ++t) {
          double u = (double)sv[t] + bb2;
          v = v + (u - v) * 0.5;
          errv = (errv + Ev[t]) * 0.5f;
          if (fabs(v - 1.0) < 2.0 * (double)errv + 1e-9) flg = true;
          float s = (v >= 1.0) ? 1.0f : 0.0f;
          if (v >= 1.0) { v = 0.0; errv = 0.f; }
          size_t idx = (size_t)(t * BN + bn) * N + col;
          if (mode == MODE_SPK) {
            ((unsigned short*)outv)[idx] = f2bf(s);
          } else if (mode == MODE_SPK_ADD) {
            float sp = bf2f(Sprev[idx]);
            if (sp != 0.f) spbits |= (1u << t);
            ((unsigned short*)outv)[idx] = f2bf(s + sp);
          } else {
            ((float*)outv)[idx] =
                (float)((double)Xres[idx] + (double)bf2f(S12[idx]) + (double)s);
          }
        }
        if (flg) {
          unsigned int rec = (unsigned int)(bn * N + col) |
                             ((unsigned int)sel << 22) | (spbits << 24);
          unsigned int ix = atomicAdd(cnt, 1u);
          if (ix < FLAG_CAP) flags[ix] = rec;
        }
      }
    }
  }
}

// ---------------------------------------------------------------------------
// f64 recompute of flagged neurons (exact vs reference). One wave per flag.
// Latency-bound strided walk -> big grid (1024 blocks) to hide latency.
// ---------------------------------------------------------------------------
__global__ __launch_bounds__(256) void fix_k(
    const void* __restrict__ A1v, const unsigned short* __restrict__ A2,
    const float* __restrict__ Wa, const float* __restrict__ Wb,
    const float* __restrict__ Wc,
    const float* __restrict__ ba, const float* __restrict__ bb,
    const float* __restrict__ bc,
    const float* __restrict__ Xres, const unsigned short* __restrict__ S12,
    void* outa, void* outb, void* outc,
    const unsigned int* __restrict__ cnt, const unsigned int* __restrict__ flags,
    int N, int K, int mode, int a1bf) {
  unsigned int count = *cnt;
  if (count > FLAG_CAP) count = FLAG_CAP;
  const int lane = threadIdx.x & 63;
  const unsigned int wgid = blockIdx.x * 4 + (threadIdx.x >> 6);
  const unsigned int nw = gridDim.x * 4;
  for (unsigned int i = wgid; i < count; i += nw) {
    unsigned int rec = flags[i];
    int idxn = (int)(rec & 0x3FFFFFu);
    int sel = (int)((rec >> 22) & 3u);
    unsigned int spb = rec >> 24;
    int bn = idxn / N;
    int col = idxn - bn * N;
    const float* W = sel == 0 ? Wa : (sel == 1 ? Wb : Wc);
    const float* bias = sel == 0 ? ba : (sel == 1 ? bb : bc);
    void* outv = sel == 0 ? outa : (sel == 1 ? outb : outc);
    double acc0 = 0, acc1 = 0, acc2 = 0, acc3 = 0;
    for (int k = lane; k < K; k += 64) {
      double w = (double)W[(size_t)k * N + col];
      double a0, a1, a2, a3;
      if (a1bf) {
        const unsigned short* A1 = (const unsigned short*)A1v;
        a0 = (double)bf2f(A1[(size_t)(0 * BN + bn) * K + k]);
        a1 = (double)bf2f(A1[(size_t)(1 * BN + bn) * K + k]);
        a2 = (double)bf2f(A1[(size_t)(2 * BN + bn) * K + k]);
        a3 = (double)bf2f(A1[(size_t)(3 * BN + bn) * K + k]);
      } else {
        const float* A1 = (const float*)A1v;
        a0 = (double)A1[(size_t)(0 * BN + bn) * K + k];
        a1 = (double)A1[(size_t)(1 * BN + bn) * K + k];
        a2 = (double)A1[(size_t)(2 * BN + bn) * K + k];
        a3 = (double)A1[(size_t)(3 * BN + bn) * K + k];
      }
      if (A2 != nullptr) {
        a0 += (double)bf2f(A2[(size_t)(0 * BN + bn) * K + k]);
        a1 += (double)bf2f(A2[(size_t)(1 * BN + bn) * K + k]);
        a2 += (double)bf2f(A2[(size_t)(2 * BN + bn) * K + k]);
        a3 += (double)bf2f(A2[(size_t)(3 * BN + bn) * K + k]);
      }
      acc0 += a0 * w; acc1 += a1 * w; acc2 += a2 * w; acc3 += a3 * w;
    }
#pragma unroll
    for (int off = 32; off >= 1; off >>= 1) {
      acc0 += __shfl_down(acc0, off);
      acc1 += __shfl_down(acc1, off);
      acc2 += __shfl_down(acc2, off);
      acc3 += __shfl_down(acc3, off);
    }
    if (lane == 0) {
      double uu[4] = {acc0, acc1, acc2, acc3};
      double v = 0.0;
#pragma unroll
      for (int t = 0; t < T_STEPS; ++t) {
        double u = uu[t] + (double)bias[col];
        v = v + (u - v) * 0.5;
        float s = (v >= 1.0) ? 1.0f : 0.0f;
        if (v >= 1.0) v = 0.0;
        size_t idx = (size_t)(t * BN + bn) * N + col;
        if (mode == MODE_SPK) {
          ((unsigned short*)outv)[idx] = f2bf(s);
        } else if (mode == MODE_SPK_ADD) {
          ((unsigned short*)outv)[idx] =
              f2bf(s + (((spb >> t) & 1u) ? 1.0f : 0.0f));
        } else {
          ((float*)outv)[idx] =
              (float)((double)Xres[idx] + (double)bf2f(S12[idx]) + (double)s);
        }
      }
    }
  }
}

// ---------------------------------------------------------------------------
// MFMA spiking attention: S = K^T V (64x64 integer <= 512, exact in f32),
// then O = 0.125 * Q @ (Sh + Sm) with S = Sh + Sm exact bf16 split.
// Output is bit-identical to the exact-integer scalar version.
// ---------------------------------------------------------------------------
__global__ __launch_bounds__(256) void attn_k(const unsigned short* __restrict__ Q,
                                              const unsigned short* __restrict__ K,
                                              const unsigned short* __restrict__ V,
                                              float* __restrict__ O) {
  __shared__ char smem[43008];
  const int blk = blockIdx.x;
  const int h = blk & 7;
  const int tb = blk >> 3;
  const size_t base = (size_t)tb * (N_TOK * D_DIM) + h * 64;
  const int tid = threadIdx.x;
  const int lane = tid & 63;
  const int wave = tid >> 6;
  const int lm = lane & 15, quad = lane >> 4;

  f32x4 sacc[4];
#pragma unroll
  for (int ct = 0; ct < 4; ++ct) sacc[ct] = (f32x4){0.f, 0.f, 0.f, 0.f};

  const int dq = wave;
  const int pi = lane;

  uint4 ka0, ka1, kb0, kb1, va0, va1, vb0, vb1;
#define ALOAD(c)                                                              \
  do {                                                                        \
    const unsigned short* kp =                                                \
        K + base + (size_t)((c) * 128 + 2 * pi) * D_DIM + dq * 16;            \
    const unsigned short* vp =                                                \
        V + base + (size_t)((c) * 128 + 2 * pi) * D_DIM + dq * 16;            \
    ka0 = *(const uint4*)(kp);     ka1 = *(const uint4*)(kp + 8);             \
    kb0 = *(const uint4*)(kp + D_DIM); kb1 = *(const uint4*)(kp + D_DIM + 8); \
    va0 = *(const uint4*)(vp);     va1 = *(const uint4*)(vp + 8);             \
    vb0 = *(const uint4*)(vp + D_DIM); vb1 = *(const uint4*)(vp + D_DIM + 8); \
  } while (0)

  ALOAD(0);
  for (int c = 0; c < 4; ++c) {
    __syncthreads();
    {
      u32 kw[8]  = {ka0.x, ka0.y, ka0.z, ka0.w, ka1.x, ka1.y, ka1.z, ka1.w};
      u32 kw2[8] = {kb0.x, kb0.y, kb0.z, kb0.w, kb1.x, kb1.y, kb1.z, kb1.w};
      u32 vw[8]  = {va0.x, va0.y, va0.z, va0.w, va1.x, va1.y, va1.z, va1.w};
      u32 vw2[8] = {vb0.x, vb0.y, vb0.z, vb0.w, vb1.x, vb1.y, vb1.z, vb1.w};
#pragma unroll
      for (int i = 0; i < 16; ++i) {
        u32 kl = (kw[i >> 1] >> ((i & 1) * 16)) & 0xffffu;
        u32 kh = (kw2[i >> 1] >> ((i & 1) * 16)) & 0xffffu;
        *(u32*)(smem + (dq * 16 + i) * 336 + pi * 4) = kl | (kh << 16);
        u32 vl = (vw[i >> 1] >> ((i & 1) * 16)) & 0xffffu;
        u32 vh = (vw2[i >> 1] >> ((i & 1) * 16)) & 0xffffu;
        *(u32*)(smem + 21504 + (dq * 16 + i) * 336 + pi * 4) = vl | (vh << 16);
      }
    }
    __syncthreads();
    if (c < 3) ALOAD(c + 1);
#pragma unroll
    for (int ks = 0; ks < 4; ++ks) {
      s16x8 a = *(const s16x8*)(smem + (wave * 16 + lm) * 336 +
                                (ks * 32 + quad * 8) * 2);
#pragma unroll
      for (int ct = 0; ct < 4; ++ct) {
        s16x8 b = *(const s16x8*)(smem + 21504 + (ct * 16 + lm) * 336 +
                                  (ks * 32 + quad * 8) * 2);
        sacc[ct] = __builtin_amdgcn_mfma_f32_16x16x32_bf16(a, b, sacc[ct], 0, 0, 0);
      }
    }
  }
#undef ALOAD
  __syncthreads();

#pragma unroll
  for (int ct = 0; ct < 4; ++ct) {
    unsigned short sh[4], sm[4];
#pragma unroll
    for (int j = 0; j < 4; ++j) {
      float s = sacc[ct][j];
      unsigned short hh = f2bf(s);
      sh[j] = hh;
      sm[j] = f2bf(s - bf2f(hh));
    }
    u32 shp0 = (u32)sh[0] | ((u32)sh[1] << 16);
    u32 shp1 = (u32)sh[2] | ((u32)sh[3] << 16);
    u32 smp0 = (u32)sm[0] | ((u32)sm[1] << 16);
    u32 smp1 = (u32)sm[2] | ((u32)sm[3] << 16);
    int row = ct * 16 + lm;
    int col = wave * 16 + quad * 4;
    uint2 wh; wh.x = shp0; wh.y = shp1;
    uint2 wm; wm.x = smp0; wm.y = smp1;
    *(uint2*)(smem + row * 176 + col * 2) = wh;
    *(uint2*)(smem + 11264 + row * 176 + col * 2) = wm;
  }
  __syncthreads();

  s16x8 bh[4][2], bm[4][2];
#pragma unroll
  for (int ct = 0; ct < 4; ++ct)
#pragma unroll
    for (int ks = 0; ks < 2; ++ks) {
      bh[ct][ks] = *(const s16x8*)(smem + (ct * 16 + lm) * 176 +
                                   (ks * 32 + quad * 8) * 2);
      bm[ct][ks] = *(const s16x8*)(smem + 11264 + (ct * 16 + lm) * 176 +
                                   (ks * 32 + quad * 8) * 2);
    }
  const int nw = wave * 128;
#pragma unroll
  for (int rt = 0; rt < 8; ++rt) {
    const int n = nw + rt * 16 + lm;
    s16x8 a0 = *(const s16x8*)(Q + base + (size_t)n * D_DIM + quad * 8);
    s16x8 a1 = *(const s16x8*)(Q + base + (size_t)n * D_DIM + 32 + quad * 8);
    f32x4 o[4];
#pragma unroll
    for (int ct = 0; ct < 4; ++ct) o[ct] = (f32x4){0.f, 0.f, 0.f, 0.f};
#pragma unroll
    for (int ct = 0; ct < 4; ++ct) {
      o[ct] = __builtin_amdgcn_mfma_f32_16x16x32_bf16(a0, bh[ct][0], o[ct], 0, 0, 0);
      o[ct] = __builtin_amdgcn_mfma_f32_16x16x32_bf16(a0, bm[ct][0], o[ct], 0, 0, 0);
      o[ct] = __builtin_amdgcn_mfma_f32_16x16x32_bf16(a1, bh[ct][1], o[ct], 0, 0, 0);
      o[ct] = __builtin_amdgcn_mfma_f32_16x16x32_bf16(a1, bm[ct][1], o[ct], 0, 0, 0);
    }
#pragma unroll
    for (int ct = 0; ct < 4; ++ct)
#pragma unroll
      for (int j = 0; j < 4; ++j) {
        int rr = nw + rt * 16 + quad * 4 + j;
        O[base + (size_t)rr * D_DIM + ct * 16 + lm] = o[ct][j] * 0.125f;
      }
  }
}

__global__ __launch_bounds__(256) void lif_plane(const float* __restrict__ U,
                                                 unsigned short* __restrict__ S) {
  int e = blockIdx.x * 256 + threadIdx.x;
  double v = 0.0;
#pragma unroll
  for (int t = 0; t < T_STEPS; ++t) {
    size_t idx = (size_t)t * (BN * D_DIM) + e;
    double u = (double)U[idx];
    v = v + (u - v) * 0.5;
    float s = (v >= 1.0) ? 1.0f : 0.0f;
    v = (v >= 1.0) ? 0.0 : v;
    S[idx] = f2bf(s);
  }
}

// ---------------------------------------------------------------------------
extern "C" void kernel_launch(void* const* d_in, const int* in_sizes, int n_in,
                              void* d_out, int out_size, void* d_ws, size_t ws_size,
                              hipStream_t stream) {
  const float* x    = (const float*)d_in[0];
  const float* enc  = (const float*)d_in[1];
  const float* Wq_s = (const float*)d_in[2];
  const float* bq_s = (const float*)d_in[3];
  const float* Wk_s = (const float*)d_in[4];
  const float* bk_s = (const float*)d_in[5];
  const float* Wv_s = (const float*)d_in[6];
  const float* bv_s = (const float*)d_in[7];
  const float* Wo_s = (const float*)d_in[8];
  const float* bo_s = (const float*)d_in[9];
  const float* Wq_c = (const float*)d_in[10];
  const float* bq_c = (const float*)d_in[11];
  const float* Wk_c = (const float*)d_in[12];
  const float* bk_c = (const float*)d_in[13];
  const float* Wv_c = (const float*)d_in[14];
  const float* bv_c = (const float*)d_in[15];
  const float* Wo_c = (const float*)d_in[16];
  const float* bo_c = (const float*)d_in[17];
  const float* W1   = (const float*)d_in[18];
  const float* b1   = (const float*)d_in[19];
  const float* W2   = (const float*)d_in[20];
  const float* b2   = (const float*)d_in[21];
  float* out = (float*)d_out;

  // ws layout (MB): 0-8 qs/as_; 8-40 ks,vs,u_attn (later h_spk over 8-40);
  // 40-48 s1; 48-56 WhT; 56-64 WmT; 64-72 Ah; 72-80 Am; 80-88 flags; 88 cnts.
  char* pool = (char*)d_ws;
  const size_t MB = 1024 * 1024;
  unsigned short* qs     = (unsigned short*)(pool + 0 * MB);
  unsigned short* ks     = (unsigned short*)(pool + 8 * MB);
  unsigned short* vs     = (unsigned short*)(pool + 16 * MB);
  float*          u_attn = (float*)(pool + 24 * MB);
  unsigned short* as_    = (unsigned short*)(pool + 0 * MB);
  unsigned short* h_spk  = (unsigned short*)(pool + 8 * MB);
  unsigned short* s1     = (unsigned short*)(pool + 40 * MB);
  unsigned short* WhT    = (unsigned short*)(pool + 48 * MB);
  unsigned short* WmT    = (unsigned short*)(pool + 56 * MB);
  unsigned short* Ahp    = (unsigned short*)(pool + 64 * MB);
  unsigned short* Amp    = (unsigned short*)(pool + 72 * MB);
  unsigned int*   flags  = (unsigned int*)(pool + 80 * MB);
  unsigned int*   cnts   = (unsigned int*)(pool + 88 * MB);

  // element offsets of each matrix inside WhT/WmT pools
  const size_t OQS = 0, OKS = 262144, OVS = 524288, OOS = 786432;
  const size_t OQC = 1048576, OKC = 1310720, OVC = 1572864, OOC = 1835008;
  const size_t OW1 = 2097152, OW2 = 3145728;

  const float ERR512 = 1.1f * 512.f * 5.96e-8f + 4.6e-5f;   // ~7.96e-5
  const float ERR2048 = 1.1f * 2048.f * 5.96e-8f + 4.6e-5f; // ~1.80e-4

  const unsigned short* NULS = nullptr;
  const float* NULF = nullptr;
  dim3 blk(256);
  int gLif = (BN * D_DIM) / 256;

  zero_k<<<1, 64, 0, stream>>>(cnts);
  wsplit_k<<<4096, blk, 0, stream>>>(Wq_s, Wk_s, Wv_s, Wo_s, Wq_c, Wk_c, Wv_c,
                                     Wo_c, W1, W2, WhT, WmT);

  // ---- Block 1: self-attention ----
  asplit_k<<<2048, blk, 0, stream>>>(x, NULS, Ahp, Amp);
  gemm_ns<<<dim3(24, 128), blk, 0, stream>>>(
      Ahp, Amp, WhT + OQS, WhT + OKS, WhT + OVS, WmT + OQS, WmT + OKS, WmT + OVS,
      bq_s, bk_s, bv_s, NULS, NULF, NULS, qs, ks, vs,
      cnts + 0, flags, 512, 512, 8, MODE_SPK, ERR512);
  fix_k<<<1024, blk, 0, stream>>>(x, NULS, Wq_s, Wk_s, Wv_s,
      bq_s, bk_s, bv_s, NULF, NULS, qs, ks, vs, cnts + 0, flags, 512, 512, MODE_SPK, 0);
  attn_k<<<128, blk, 0, stream>>>(qs, ks, vs, u_attn);
  lif_plane<<<gLif, blk, 0, stream>>>(u_attn, as_);
  gemm_ns<<<dim3(8, 128), blk, 0, stream>>>(
      as_, NULS, WhT + OOS, WhT + OOS, WhT + OOS, WmT + OOS, WmT + OOS, WmT + OOS,
      bo_s, bo_s, bo_s, NULS, NULF, NULS, s1, s1, s1,
      cnts + 1, flags, 512, 512, 8, MODE_SPK, ERR512);
  fix_k<<<1024, blk, 0, stream>>>(as_, NULS, Wo_s, Wo_s, Wo_s,
      bo_s, bo_s, bo_s, NULF, NULS, s1, s1, s1, cnts + 1, flags, 512, 512, MODE_SPK, 1);

  // ---- Block 2: cross-attention ----
  asplit_k<<<2048, blk, 0, stream>>>(x, s1, Ahp, Amp);
  gemm_ns<<<dim3(8, 128), blk, 0, stream>>>(
      Ahp, Amp, WhT + OQC, WhT + OQC, WhT + OQC, WmT + OQC, WmT + OQC, WmT + OQC,
      bq_c, bq_c, bq_c, NULS, NULF, NULS, qs, qs, qs,
      cnts + 2, flags, 512, 512, 8, MODE_SPK, ERR512);
  fix_k<<<1024, blk, 0, stream>>>(x, s1, Wq_c, Wq_c, Wq_c,
      bq_c, bq_c, bq_c, NULF, NULS, qs, qs, qs, cnts + 2, flags, 512, 512, MODE_SPK, 0);
  asplit_k<<<2048, blk, 0, stream>>>(enc, NULS, Ahp, Amp);
  gemm_ns<<<dim3(16, 128), blk, 0, stream>>>(
      Ahp, Amp, WhT + OKC, WhT + OVC, WhT + OVC, WmT + OKC, WmT + OVC, WmT + OVC,
      bk_c, bv_c, bv_c, NULS, NULF, NULS, ks, vs, vs,
      cnts + 3, flags, 512, 512, 8, MODE_SPK, ERR512);
  fix_k<<<1024, blk, 0, stream>>>(enc, NULS, Wk_c, Wv_c, Wv_c,
      bk_c, bv_c, bv_c, NULF, NULS, ks, vs, vs, cnts + 3, flags, 512, 512, MODE_SPK, 0);
  attn_k<<<128, blk, 0, stream>>>(qs, ks, vs, u_attn);
  lif_plane<<<gLif, blk, 0, stream>>>(u_attn, as_);
  gemm_ns<<<dim3(8, 128), blk, 0, stream>>>(
      as_, NULS, WhT + OOC, WhT + OOC, WhT + OOC, WmT + OOC, WmT + OOC, WmT + OOC,
      bo_c, bo_c, bo_c, s1, NULF, NULS, s1, s1, s1,
      cnts + 4, flags, 512, 512, 8, MODE_SPK_ADD, ERR512);
  fix_k<<<1024, blk, 0, stream>>>(as_, NULS, Wo_c, Wo_c, Wo_c,
      bo_c, bo_c, bo_c, NULF, NULS, s1, s1, s1, cnts + 4, flags, 512, 512, MODE_SPK_ADD, 1);

  // ---- Block 3: spiking MLP ----
  asplit_k<<<2048, blk, 0, stream>>>(x, s1, Ahp, Amp);
  gemm_ns<<<dim3(32, 128), blk, 0, stream>>>(
      Ahp, Amp, WhT + OW1, WhT + OW1, WhT + OW1, WmT + OW1, WmT + OW1, WmT + OW1,
      b1, b1, b1, NULS, NULF, NULS, h_spk, h_spk, h_spk,
      cnts + 5, flags, 2048, 512, 32, MODE_SPK, ERR512);
  fix_k<<<1024, blk, 0, stream>>>(x, s1, W1, W1, W1,
      b1, b1, b1, NULF, NULS, h_spk, h_spk, h_spk, cnts + 5, flags, 2048, 512, MODE_SPK, 0);
  gemm_ns<<<dim3(8, 128), blk, 0, stream>>>(
      h_spk, NULS, WhT + OW2, WhT + OW2, WhT + OW2, WmT + OW2, WmT + OW2, WmT + OW2,
      b2, b2, b2, NULS, x, s1, out, out, out,
      cnts + 6, flags, 512, 2048, 8, MODE_OUT, ERR2048);
  fix_k<<<1024, blk, 0, stream>>>(h_spk, NULS, W2, W2, W2,
      b2, b2, b2, x, s1, out, out, out, cnts + 6, flags, 512, 2048, MODE_OUT, 1);

  (void)in_sizes; (void)n_in; (void)out_size; (void)ws_size;
}

// Round 8
// 690.820 us; speedup vs baseline: 1.3435x; 1.3435x over previous
//
#include <hip/hip_runtime.h>
#include <cstddef>

// DecoderLayer: T=4, B=4, N=512, D=512, F=2048, H=8, head_dim=64
// I/O: float32. Round 16: revert to round-13 structure (proven 721us; B back
// in LDS — rounds 14/15's direct-global B was a verified regression), plus
// BK=64: two 32-k chunks staged per barrier pair. Halves barrier drains
// (the m233-style 2-phase stall), same MFMA order -> bit-identical numerics.
// LDS 36864 B/block, 4 blocks/CU (147KB<160KB); prefetch 8x uint4 (~120 regs,
// under the 128-reg/4-wave occupancy step).
#define T_STEPS 4
#define BN 2048
#define N_TOK 512
#define D_DIM 512
#define F_DIM 2048

#define MODE_SPK 0
#define MODE_SPK_ADD 1
#define MODE_OUT 2

#define FLAG_CAP (2u * 1024u * 1024u)

typedef float f32x4 __attribute__((ext_vector_type(4)));
typedef short s16x8 __attribute__((ext_vector_type(8)));
typedef unsigned int u32;

__device__ __forceinline__ float bf2f(unsigned short u) {
  unsigned int x = ((unsigned int)u) << 16;
  float f;
  __builtin_memcpy(&f, &x, 4);
  return f;
}
__device__ __forceinline__ unsigned short f2bf(float f) {
  unsigned int x;
  __builtin_memcpy(&x, &f, 4);
  x += 0x7fffu + ((x >> 16) & 1u);  // RNE
  return (unsigned short)(x >> 16);
}

// ---------------------------------------------------------------------------
// Weight preprocessing: for each W [K,N] f32 produce bf16 split transposed
// planes WhT, WmT [N,K] with w = wh + wm + r, |r| <= 2^-16|w|.
// ---------------------------------------------------------------------------
__global__ __launch_bounds__(256) void wsplit_k(
    const float* w0, const float* w1, const float* w2, const float* w3,
    const float* w4, const float* w5, const float* w6, const float* w7,
    const float* w8, const float* w9,
    unsigned short* __restrict__ WhT, unsigned short* __restrict__ WmT) {
  __shared__ float T[32][33];
  const int tile = blockIdx.x;
  const float* w;
  int Kd, Nd, lt;
  size_t off;
  if (tile < 2048) {
    const float* ws[8] = {w0, w1, w2, w3, w4, w5, w6, w7};
    int m = tile >> 8;
    lt = tile & 255; Kd = 512; Nd = 512; off = (size_t)m * 262144; w = ws[m];
  } else if (tile < 3072) {
    lt = tile - 2048; Kd = 512; Nd = 2048; off = 2097152; w = w8;
  } else {
    lt = tile - 3072; Kd = 2048; Nd = 512; off = 3145728; w = w9;
  }
  const int tilesK = Kd / 32;
  const int tk = lt % tilesK, tn = lt / tilesK;
  {
    int r = threadIdx.x >> 3, c4 = (threadIdx.x & 7) * 4;
    float4 v = *reinterpret_cast<const float4*>(
        w + (size_t)(tk * 32 + r) * Nd + tn * 32 + c4);
    T[r][c4 + 0] = v.x; T[r][c4 + 1] = v.y;
    T[r][c4 + 2] = v.z; T[r][c4 + 3] = v.w;
  }
  __syncthreads();
  {
    int n = threadIdx.x >> 3, k4 = (threadIdx.x & 7) * 4;
    float wv[4];
#pragma unroll
    for (int j = 0; j < 4; ++j) wv[j] = T[k4 + j][n];
    size_t ob = off + (size_t)(tn * 32 + n) * Kd + tk * 32 + k4;
    ushort4 h, m2;
    unsigned short* hp = &h.x; unsigned short* mp = &m2.x;
#pragma unroll
    for (int j = 0; j < 4; ++j) {
      unsigned short hh = f2bf(wv[j]);
      float r = wv[j] - bf2f(hh);   // exact
      hp[j] = hh; mp[j] = f2bf(r);
    }
    *reinterpret_cast<ushort4*>(WhT + ob) = h;
    *reinterpret_cast<ushort4*>(WmT + ob) = m2;
  }
}

__global__ void zero_k(unsigned int* c) {
  if (threadIdx.x < 8) c[threadIdx.x] = 0u;
}

// ---------------------------------------------------------------------------
// A-operand split: av = A1 (f32) [+ bf2f(A2)]; Ah = bf16(av), Am = bf16(av-Ah).
// ---------------------------------------------------------------------------
__global__ __launch_bounds__(256) void asplit_k(
    const float* __restrict__ A1, const unsigned short* __restrict__ A2,
    unsigned short* __restrict__ Ah, unsigned short* __restrict__ Am) {
  const size_t base = ((size_t)blockIdx.x * 256 + threadIdx.x) * 8;
  float4 f0 = *reinterpret_cast<const float4*>(A1 + base);
  float4 f1 = *reinterpret_cast<const float4*>(A1 + base + 4);
  float av[8] = {f0.x, f0.y, f0.z, f0.w, f1.x, f1.y, f1.z, f1.w};
  if (A2 != nullptr) {
    uint4 s = *reinterpret_cast<const uint4*>(A2 + base);
    const unsigned int* pu = &s.x;
#pragma unroll
    for (int j = 0; j < 4; ++j) {
      av[2 * j]     += bf2f((unsigned short)(pu[j] & 0xffffu));
      av[2 * j + 1] += bf2f((unsigned short)(pu[j] >> 16));
    }
  }
  unsigned int ph[4], pm[4];
#pragma unroll
  for (int j = 0; j < 4; ++j) {
    unsigned short h0 = f2bf(av[2 * j]);
    unsigned short h1 = f2bf(av[2 * j + 1]);
    float r0 = av[2 * j] - bf2f(h0);
    float r1 = av[2 * j + 1] - bf2f(h1);
    ph[j] = (unsigned int)h0 | ((unsigned int)h1 << 16);
    pm[j] = (unsigned int)f2bf(r0) | ((unsigned int)f2bf(r1) << 16);
  }
  uint4 vh; vh.x = ph[0]; vh.y = ph[1]; vh.z = ph[2]; vh.w = ph[3];
  uint4 vm; vm.x = pm[0]; vm.y = pm[1]; vm.z = pm[2]; vm.w = pm[3];
  *reinterpret_cast<uint4*>(Ah + base) = vh;
  *reinterpret_cast<uint4*>(Am + base) = vm;
}

// ---------------------------------------------------------------------------
// Split-precision bf16-MFMA GEMM + LIF over T + uncertainty flagging.
// Block tile 64 rows (16 bn x 4 t) x 64 cols; 4 waves, wave tile 32x32 =
// 2x2 mfma 16x16x32. BK=64: each barrier pair stages a 64-deep K-slab of all
// four planes into LDS (row stride 144 B, 2-way-per-quarter-wave benign);
// two 32-k sub-steps execute in the original order -> bit-identical.
// acc_hi += ah*bh; acc_mid += ah*bm (+ am*bh if Am); acc_abs += |ah|*|bh|.
// u = f64(hi+mid)+bias, E = errC*abs; flagged -> f64 recompute (fix_k).
// Grid: (nxb*ngemm, BN/16), block 256.
// ---------------------------------------------------------------------------
__global__ __launch_bounds__(256, 4) void gemm_ns(
    const unsigned short* __restrict__ Ah, const unsigned short* __restrict__ Am,
    const unsigned short* __restrict__ WhTa, const unsigned short* __restrict__ WhTb,
    const unsigned short* __restrict__ WhTc,
    const unsigned short* __restrict__ WmTa, const unsigned short* __restrict__ WmTb,
    const unsigned short* __restrict__ WmTc,
    const float* __restrict__ ba, const float* __restrict__ bb,
    const float* __restrict__ bc,
    const unsigned short* Sprev, const float* __restrict__ Xres,
    const unsigned short* __restrict__ S12,
    void* outa, void* outb, void* outc,
    unsigned int* __restrict__ cnt, unsigned int* __restrict__ flags,
    int N, int K, int nxb, int mode, float errC) {
  // LDS 36864 B: Ah@0, Am@9216, Bh@18432, Bm@27648; each 64 rows x 64 k bf16,
  // row stride 72 elems (144 B, 16B-aligned).
  // Epilogue overlay: UXS f32[16][128]@0 (8 KB), UXA @8192 (8 KB).
  __shared__ char smem[36864];

  const int sel = (int)blockIdx.x / nxb;
  const int nb = (int)blockIdx.x - sel * nxb;
  const unsigned short* WhT = sel == 0 ? WhTa : (sel == 1 ? WhTb : WhTc);
  const unsigned short* WmT = sel == 0 ? WmTa : (sel == 1 ? WmTb : WmTc);
  const float* bias = sel == 0 ? ba : (sel == 1 ? bb : bc);
  void* outv = sel == 0 ? outa : (sel == 1 ? outb : outc);
  const bool hasAm = (Am != nullptr);

  const int tid = threadIdx.x;
  const int lane = tid & 63;
  const int wave = tid >> 6;
  const int wr = wave >> 1, wcq = wave & 1;
  const int lm = lane & 15, quad = lane >> 4;
  const int n0 = nb * 64;
  const int bn0 = (int)blockIdx.y * 16;

  // staging roles: srow = A tile-row / B tile-col (0..63), skg = k-octet
  const int srow = tid >> 2;
  const int skg = tid & 3;
  const size_t aoff_row = (size_t)((srow >> 4) * BN + bn0 + (srow & 15)) * K;
  const size_t boff_row = (size_t)(n0 + srow) * K;

  f32x4 accH[2][2], accM[2][2], accA[2][2];
#pragma unroll
  for (int i = 0; i < 2; ++i)
#pragma unroll
    for (int j = 0; j < 2; ++j) {
      accH[i][j] = (f32x4){0.f, 0.f, 0.f, 0.f};
      accM[i][j] = (f32x4){0.f, 0.f, 0.f, 0.f};
      accA[i][j] = (f32x4){0.f, 0.f, 0.f, 0.f};
    }

  // prefetch registers: 2x uint4 per plane (k 0..31 and 32..63 octets)
  uint4 pah0 = {0,0,0,0}, pah1 = {0,0,0,0};
  uint4 pam0 = {0,0,0,0}, pam1 = {0,0,0,0};
  uint4 pwh0, pwh1, pwm0, pwm1;

#define LOAD_TILE(K0)                                                          \
  do {                                                                         \
    pah0 = *reinterpret_cast<const uint4*>(Ah + aoff_row + (K0) + skg * 8);    \
    pah1 = *reinterpret_cast<const uint4*>(Ah + aoff_row + (K0) + 32 + skg * 8);\
    if (hasAm) {                                                               \
      pam0 = *reinterpret_cast<const uint4*>(Am + aoff_row + (K0) + skg * 8);  \
      pam1 = *reinterpret_cast<const uint4*>(Am + aoff_row + (K0) + 32 + skg * 8);\
    }                                                                          \
    pwh0 = *reinterpret_cast<const uint4*>(WhT + boff_row + (K0) + skg * 8);   \
    pwh1 = *reinterpret_cast<const uint4*>(WhT + boff_row + (K0) + 32 + skg * 8);\
    pwm0 = *reinterpret_cast<const uint4*>(WmT + boff_row + (K0) + skg * 8);   \
    pwm1 = *reinterpret_cast<const uint4*>(WmT + boff_row + (K0) + 32 + skg * 8);\
  } while (0)

#define STAGE()                                                                \
  do {                                                                         \
    char* p = smem + srow * 144 + skg * 16;                                    \
    *reinterpret_cast<uint4*>(p + 0) = pah0;                                   \
    *reinterpret_cast<uint4*>(p + 64) = pah1;                                  \
    if (hasAm) {                                                               \
      *reinterpret_cast<uint4*>(p + 9216) = pam0;                              \
      *reinterpret_cast<uint4*>(p + 9216 + 64) = pam1;                         \
    }                                                                          \
    *reinterpret_cast<uint4*>(p + 18432) = pwh0;                               \
    *reinterpret_cast<uint4*>(p + 18432 + 64) = pwh1;                          \
    *reinterpret_cast<uint4*>(p + 27648) = pwm0;                               \
    *reinterpret_cast<uint4*>(p + 27648 + 64) = pwm1;                          \
  } while (0)

  const int aoff0 = (wr * 32 + lm) * 144 + quad * 16;
  const int aoff1 = aoff0 + 16 * 144;
  const int boff0 = (wcq * 32 + lm) * 144 + quad * 16;
  const int boff1 = boff0 + 16 * 144;

  LOAD_TILE(0);
  for (int k0 = 0; k0 < K; k0 += 64) {
    STAGE();
    __syncthreads();
    if (k0 + 64 < K) LOAD_TILE(k0 + 64);
#pragma unroll
    for (int kk = 0; kk < 2; ++kk) {
      const int kb = kk * 64;  // byte offset of the 32-k sub-step
      s16x8 aH0 = *reinterpret_cast<const s16x8*>(smem + 0 + aoff0 + kb);
      s16x8 aH1 = *reinterpret_cast<const s16x8*>(smem + 0 + aoff1 + kb);
      s16x8 bH0 = *reinterpret_cast<const s16x8*>(smem + 18432 + boff0 + kb);
      s16x8 bH1 = *reinterpret_cast<const s16x8*>(smem + 18432 + boff1 + kb);
      s16x8 bM0 = *reinterpret_cast<const s16x8*>(smem + 27648 + boff0 + kb);
      s16x8 bM1 = *reinterpret_cast<const s16x8*>(smem + 27648 + boff1 + kb);
      s16x8 aA0 = aH0 & (short)0x7FFF;
      s16x8 aA1 = aH1 & (short)0x7FFF;
      s16x8 bA0 = bH0 & (short)0x7FFF;
      s16x8 bA1 = bH1 & (short)0x7FFF;
      accH[0][0] = __builtin_amdgcn_mfma_f32_16x16x32_bf16(aH0, bH0, accH[0][0], 0, 0, 0);
      accH[0][1] = __builtin_amdgcn_mfma_f32_16x16x32_bf16(aH0, bH1, accH[0][1], 0, 0, 0);
      accH[1][0] = __builtin_amdgcn_mfma_f32_16x16x32_bf16(aH1, bH0, accH[1][0], 0, 0, 0);
      accH[1][1] = __builtin_amdgcn_mfma_f32_16x16x32_bf16(aH1, bH1, accH[1][1], 0, 0, 0);
      accM[0][0] = __builtin_amdgcn_mfma_f32_16x16x32_bf16(aH0, bM0, accM[0][0], 0, 0, 0);
      accM[0][1] = __builtin_amdgcn_mfma_f32_16x16x32_bf16(aH0, bM1, accM[0][1], 0, 0, 0);
      accM[1][0] = __builtin_amdgcn_mfma_f32_16x16x32_bf16(aH1, bM0, accM[1][0], 0, 0, 0);
      accM[1][1] = __builtin_amdgcn_mfma_f32_16x16x32_bf16(aH1, bM1, accM[1][1], 0, 0, 0);
      if (hasAm) {
        s16x8 aM0 = *reinterpret_cast<const s16x8*>(smem + 9216 + aoff0 + kb);
        s16x8 aM1 = *reinterpret_cast<const s16x8*>(smem + 9216 + aoff1 + kb);
        accM[0][0] = __builtin_amdgcn_mfma_f32_16x16x32_bf16(aM0, bH0, accM[0][0], 0, 0, 0);
        accM[0][1] = __builtin_amdgcn_mfma_f32_16x16x32_bf16(aM0, bH1, accM[0][1], 0, 0, 0);
        accM[1][0] = __builtin_amdgcn_mfma_f32_16x16x32_bf16(aM1, bH0, accM[1][0], 0, 0, 0);
        accM[1][1] = __builtin_amdgcn_mfma_f32_16x16x32_bf16(aM1, bH1, accM[1][1], 0, 0, 0);
      }
      accA[0][0] = __builtin_amdgcn_mfma_f32_16x16x32_bf16(aA0, bA0, accA[0][0], 0, 0, 0);
      accA[0][1] = __builtin_amdgcn_mfma_f32_16x16x32_bf16(aA0, bA1, accA[0][1], 0, 0, 0);
      accA[1][0] = __builtin_amdgcn_mfma_f32_16x16x32_bf16(aA1, bA0, accA[1][0], 0, 0, 0);
      accA[1][1] = __builtin_amdgcn_mfma_f32_16x16x32_bf16(aA1, bA1, accA[1][1], 0, 0, 0);
    }
    __syncthreads();
  }
#undef LOAD_TILE
#undef STAGE

  // ---- epilogue ----
  float* UXS = (float*)smem;
  float* UXA = (float*)(smem + 8192);
  if (wr == 1) {
#pragma unroll
    for (int mt = 0; mt < 2; ++mt)
#pragma unroll
      for (int nt = 0; nt < 2; ++nt)
#pragma unroll
        for (int j = 0; j < 4; ++j) {
          int i = mt * 8 + nt * 4 + j;
          UXS[i * 128 + wcq * 64 + lane] = accH[mt][nt][j] + accM[mt][nt][j];
          UXA[i * 128 + wcq * 64 + lane] = accA[mt][nt][j];
        }
  }
  __syncthreads();
  if (wr == 0) {
#pragma unroll
    for (int nt = 0; nt < 2; ++nt) {
      const int col = n0 + wcq * 32 + nt * 16 + lm;
      const double bb2 = (double)bias[col];
#pragma unroll
      for (int j = 0; j < 4; ++j) {
        const int bn = bn0 + quad * 4 + j;
        float sv[4], Ev[4];
        sv[0] = accH[0][nt][j] + accM[0][nt][j];
        sv[1] = accH[1][nt][j] + accM[1][nt][j];
        sv[2] = UXS[(0 * 8 + nt * 4 + j) * 128 + wcq * 64 + lane];
        sv[3] = UXS[(1 * 8 + nt * 4 + j) * 128 + wcq * 64 + lane];
        Ev[0] = errC * accA[0][nt][j];
        Ev[1] = errC * accA[1][nt][j];
        Ev[2] = errC * UXA[(0 * 8 + nt * 4 + j) * 128 + wcq * 64 + lane];
        Ev[3] = errC * UXA[(1 * 8 + nt * 4 + j) * 128 + wcq * 64 + lane];
        double v = 0.0;
        float errv = 0.f;
        bool flg = false;
        unsigned int spbits = 0;
#pragma unroll
        for (int t = 0; t < T_STEPS; ++t) {
          double u = (double)sv[t] + bb2;
          v = v + (u - v) * 0.5;
          errv = (errv + Ev[t]) * 0.5f;
          if (fabs(v - 1.0) < 2.0 * (double)errv + 1e-9) flg = true;
          float s = (v >= 1.0) ? 1.0f : 0.0f;
          if (v >= 1.0) { v = 0.0; errv = 0.f; }
          size_t idx = (size_t)(t * BN + bn) * N + col;
          if (mode == MODE_SPK) {
            ((unsigned short*)outv)[idx] = f2bf(s);
          } else if (mode == MODE_SPK_ADD) {
            float sp = bf2f(Sprev[idx]);
            if (sp != 0.f) spbits |= (1u << t);
            ((unsigned short*)outv)[idx] = f2bf(s + sp);
          } else {
            ((float*)outv)[idx] =
                (float)((double)Xres[idx] + (double)bf2f(S12[idx]) + (double)s);
          }
        }
        if (flg) {
          unsigned int rec = (unsigned int)(bn * N + col) |
                             ((unsigned int)sel << 22) | (spbits << 24);
          unsigned int ix = atomicAdd(cnt, 1u);
          if (ix < FLAG_CAP) flags[ix] = rec;
        }
      }
    }
  }
}

// ---------------------------------------------------------------------------
// f64 recompute of flagged neurons (exact vs reference). One wave per flag.
// Latency-bound strided walk -> big grid (1024 blocks) to hide latency.
// ---------------------------------------------------------------------------
__global__ __launch_bounds__(256) void fix_k(
    const void* __restrict__ A1v, const unsigned short* __restrict__ A2,
    const float* __restrict__ Wa, const float* __restrict__ Wb,
    const float* __restrict__ Wc,
    const float* __restrict__ ba, const float* __restrict__ bb,
    const float* __restrict__ bc,
    const float* __restrict__ Xres, const unsigned short* __restrict__ S12,
    void* outa, void* outb, void* outc,
    const unsigned int* __restrict__ cnt, const unsigned int* __restrict__ flags,
    int N, int K, int mode, int a1bf) {
  unsigned int count = *cnt;
  if (count > FLAG_CAP) count = FLAG_CAP;
  const int lane = threadIdx.x & 63;
  const unsigned int wgid = blockIdx.x * 4 + (threadIdx.x >> 6);
  const unsigned int nw = gridDim.x * 4;
  for (unsigned int i = wgid; i < count; i += nw) {
    unsigned int rec = flags[i];
    int idxn = (int)(rec & 0x3FFFFFu);
    int sel = (int)((rec >> 22) & 3u);
    unsigned int spb = rec >> 24;
    int bn = idxn / N;
    int col = idxn - bn * N;
    const float* W = sel == 0 ? Wa : (sel == 1 ? Wb : Wc);
    const float* bias = sel == 0 ? ba : (sel == 1 ? bb : bc);
    void* outv = sel == 0 ? outa : (sel == 1 ? outb : outc);
    double acc0 = 0, acc1 = 0, acc2 = 0, acc3 = 0;
    for (int k = lane; k < K; k += 64) {
      double w = (double)W[(size_t)k * N + col];
      double a0, a1, a2, a3;
      if (a1bf) {
        const unsigned short* A1 = (const unsigned short*)A1v;
        a0 = (double)bf2f(A1[(size_t)(0 * BN + bn) * K + k]);
        a1 = (double)bf2f(A1[(size_t)(1 * BN + bn) * K + k]);
        a2 = (double)bf2f(A1[(size_t)(2 * BN + bn) * K + k]);
        a3 = (double)bf2f(A1[(size_t)(3 * BN + bn) * K + k]);
      } else {
        const float* A1 = (const float*)A1v;
        a0 = (double)A1[(size_t)(0 * BN + bn) * K + k];
        a1 = (double)A1[(size_t)(1 * BN + bn) * K + k];
        a2 = (double)A1[(size_t)(2 * BN + bn) * K + k];
        a3 = (double)A1[(size_t)(3 * BN + bn) * K + k];
      }
      if (A2 != nullptr) {
        a0 += (double)bf2f(A2[(size_t)(0 * BN + bn) * K + k]);
        a1 += (double)bf2f(A2[(size_t)(1 * BN + bn) * K + k]);
        a2 += (double)bf2f(A2[(size_t)(2 * BN + bn) * K + k]);
        a3 += (double)bf2f(A2[(size_t)(3 * BN + bn) * K + k]);
      }
      acc0 += a0 * w; acc1 += a1 * w; acc2 += a2 * w; acc3 += a3 * w;
    }
#pragma unroll
    for (int off = 32; off >= 1; off >>= 1) {
      acc0 += __shfl_down(acc0, off);
      acc1 += __shfl_down(acc1, off);
      acc2 += __shfl_down(acc2, off);
      acc3 += __shfl_down(acc3, off);
    }
    if (lane == 0) {
      double uu[4] = {acc0, acc1, acc2, acc3};
      double v = 0.0;
#pragma unroll
      for (int t = 0; t < T_STEPS; ++t) {
        double u = uu[t] + (double)bias[col];
        v = v + (u - v) * 0.5;
        float s = (v >= 1.0) ? 1.0f : 0.0f;
        if (v >= 1.0) v = 0.0;
        size_t idx = (size_t)(t * BN + bn) * N + col;
        if (mode == MODE_SPK) {
          ((unsigned short*)outv)[idx] = f2bf(s);
        } else if (mode == MODE_SPK_ADD) {
          ((unsigned short*)outv)[idx] =
              f2bf(s + (((spb >> t) & 1u) ? 1.0f : 0.0f));
        } else {
          ((float*)outv)[idx] =
              (float)((double)Xres[idx] + (double)bf2f(S12[idx]) + (double)s);
        }
      }
    }
  }
}

// ---------------------------------------------------------------------------
// MFMA spiking attention: S = K^T V (64x64 integer <= 512, exact in f32),
// then O = 0.125 * Q @ (Sh + Sm) with S = Sh + Sm exact bf16 split.
// Output is bit-identical to the exact-integer scalar version.
// ---------------------------------------------------------------------------
__global__ __launch_bounds__(256) void attn_k(const unsigned short* __restrict__ Q,
                                              const unsigned short* __restrict__ K,
                                              const unsigned short* __restrict__ V,
                                              float* __restrict__ O) {
  __shared__ char smem[43008];
  const int blk = blockIdx.x;
  const int h = blk & 7;
  const int tb = blk >> 3;
  const size_t base = (size_t)tb * (N_TOK * D_DIM) + h * 64;
  const int tid = threadIdx.x;
  const int lane = tid & 63;
  const int wave = tid >> 6;
  const int lm = lane & 15, quad = lane >> 4;

  f32x4 sacc[4];
#pragma unroll
  for (int ct = 0; ct < 4; ++ct) sacc[ct] = (f32x4){0.f, 0.f, 0.f, 0.f};

  const int dq = wave;
  const int pi = lane;

  uint4 ka0, ka1, kb0, kb1, va0, va1, vb0, vb1;
#define ALOAD(c)                                                              \
  do {                                                                        \
    const unsigned short* kp =                                                \
        K + base + (size_t)((c) * 128 + 2 * pi) * D_DIM + dq * 16;            \
    const unsigned short* vp =                                                \
        V + base + (size_t)((c) * 128 + 2 * pi) * D_DIM + dq * 16;            \
    ka0 = *(const uint4*)(kp);     ka1 = *(const uint4*)(kp + 8);             \
    kb0 = *(const uint4*)(kp + D_DIM); kb1 = *(const uint4*)(kp + D_DIM + 8); \
    va0 = *(const uint4*)(vp);     va1 = *(const uint4*)(vp + 8);             \
    vb0 = *(const uint4*)(vp + D_DIM); vb1 = *(const uint4*)(vp + D_DIM + 8); \
  } while (0)

  ALOAD(0);
  for (int c = 0; c < 4; ++c) {
    __syncthreads();
    {
      u32 kw[8]  = {ka0.x, ka0.y, ka0.z, ka0.w, ka1.x, ka1.y, ka1.z, ka1.w};
      u32 kw2[8] = {kb0.x, kb0.y, kb0.z, kb0.w, kb1.x, kb1.y, kb1.z, kb1.w};
      u32 vw[8]  = {va0.x, va0.y, va0.z, va0.w, va1.x, va1.y, va1.z, va1.w};
      u32 vw2[8] = {vb0.x, vb0.y, vb0.z, vb0.w, vb1.x, vb1.y, vb1.z, vb1.w};
#pragma unroll
      for (int i = 0; i < 16; ++i) {
        u32 kl = (kw[i >> 1] >> ((i & 1) * 16)) & 0xffffu;
        u32 kh = (kw2[i >> 1] >> ((i & 1) * 16)) & 0xffffu;
        *(u32*)(smem + (dq * 16 + i) * 336 + pi * 4) = kl | (kh << 16);
        u32 vl = (vw[i >> 1] >> ((i & 1) * 16)) & 0xffffu;
        u32 vh = (vw2[i >> 1] >> ((i & 1) * 16)) & 0xffffu;
        *(u32*)(smem + 21504 + (dq * 16 + i) * 336 + pi * 4) = vl | (vh << 16);
      }
    }
    __syncthreads();
    if (c < 3) ALOAD(c + 1);
#pragma unroll
    for (int ks = 0; ks < 4; ++ks) {
      s16x8 a = *(const s16x8*)(smem + (wave * 16 + lm) * 336 +
                                (ks * 32 + quad * 8) * 2);
#pragma unroll
      for (int ct = 0; ct < 4; ++ct) {
        s16x8 b = *(const s16x8*)(smem + 21504 + (ct * 16 + lm) * 336 +
                                  (ks * 32 + quad * 8) * 2);
        sacc[ct] = __builtin_amdgcn_mfma_f32_16x16x32_bf16(a, b, sacc[ct], 0, 0, 0);
      }
    }
  }
#undef ALOAD
  __syncthreads();

#pragma unroll
  for (int ct = 0; ct < 4; ++ct) {
    unsigned short sh[4], sm[4];
#pragma unroll
    for (int j = 0; j < 4; ++j) {
      float s = sacc[ct][j];
      unsigned short hh = f2bf(s);
      sh[j] = hh;
      sm[j] = f2bf(s - bf2f(hh));
    }
    u32 shp0 = (u32)sh[0] | ((u32)sh[1] << 16);
    u32 shp1 = (u32)sh[2] | ((u32)sh[3] << 16);
    u32 smp0 = (u32)sm[0] | ((u32)sm[1] << 16);
    u32 smp1 = (u32)sm[2] | ((u32)sm[3] << 16);
    int row = ct * 16 + lm;
    int col = wave * 16 + quad * 4;
    uint2 wh; wh.x = shp0; wh.y = shp1;
    uint2 wm; wm.x = smp0; wm.y = smp1;
    *(uint2*)(smem + row * 176 + col * 2) = wh;
    *(uint2*)(smem + 11264 + row * 176 + col * 2) = wm;
  }
  __syncthreads();

  s16x8 bh[4][2], bm[4][2];
#pragma unroll
  for (int ct = 0; ct < 4; ++ct)
#pragma unroll
    for (int ks = 0; ks < 2; ++ks) {
      bh[ct][ks] = *(const s16x8*)(smem + (ct * 16 + lm) * 176 +
                                   (ks * 32 + quad * 8) * 2);
      bm[ct][ks] = *(const s16x8*)(smem + 11264 + (ct * 16 + lm) * 176 +
                                   (ks * 32 + quad * 8) * 2);
    }
  const int nw = wave * 128;
#pragma unroll
  for (int rt = 0; rt < 8; ++rt) {
    const int n = nw + rt * 16 + lm;
    s16x8 a0 = *(const s16x8*)(Q + base + (size_t)n * D_DIM + quad * 8);
    s16x8 a1 = *(const s16x8*)(Q + base + (size_t)n * D_DIM + 32 + quad * 8);
    f32x4 o[4];
#pragma unroll
    for (int ct = 0; ct < 4; ++ct) o[ct] = (f32x4){0.f, 0.f, 0.f, 0.f};
#pragma unroll
    for (int ct = 0; ct < 4; ++ct) {
      o[ct] = __builtin_amdgcn_mfma_f32_16x16x32_bf16(a0, bh[ct][0], o[ct], 0, 0, 0);
      o[ct] = __builtin_amdgcn_mfma_f32_16x16x32_bf16(a0, bm[ct][0], o[ct], 0, 0, 0);
      o[ct] = __builtin_amdgcn_mfma_f32_16x16x32_bf16(a1, bh[ct][1], o[ct], 0, 0, 0);
      o[ct] = __builtin_amdgcn_mfma_f32_16x16x32_bf16(a1, bm[ct][1], o[ct], 0, 0, 0);
    }
#pragma unroll
    for (int ct = 0; ct < 4; ++ct)
#pragma unroll
      for (int j = 0; j < 4; ++j) {
        int rr = nw + rt * 16 + quad * 4 + j;
        O[base + (size_t)rr * D_DIM + ct * 16 + lm] = o[ct][j] * 0.125f;
      }
  }
}

__global__ __launch_bounds__(256) void lif_plane(const float* __restrict__ U,
                                                 unsigned short* __restrict__ S) {
  int e = blockIdx.x * 256 + threadIdx.x;
  double v = 0.0;
#pragma unroll
  for (int t = 0; t < T_STEPS; ++t) {
    size_t idx = (size_t)t * (BN * D_DIM) + e;
    double u = (double)U[idx];
    v = v + (u - v) * 0.5;
    float s = (v >= 1.0) ? 1.0f : 0.0f;
    v = (v >= 1.0) ? 0.0 : v;
    S[idx] = f2bf(s);
  }
}

// ---------------------------------------------------------------------------
extern "C" void kernel_launch(void* const* d_in, const int* in_sizes, int n_in,
                              void* d_out, int out_size, void* d_ws, size_t ws_size,
                              hipStream_t stream) {
  const float* x    = (const float*)d_in[0];
  const float* enc  = (const float*)d_in[1];
  const float* Wq_s = (const float*)d_in[2];
  const float* bq_s = (const float*)d_in[3];
  const float* Wk_s = (const float*)d_in[4];
  const float* bk_s = (const float*)d_in[5];
  const float* Wv_s = (const float*)d_in[6];
  const float* bv_s = (const float*)d_in[7];
  const float* Wo_s = (const float*)d_in[8];
  const float* bo_s = (const float*)d_in[9];
  const float* Wq_c = (const float*)d_in[10];
  const float* bq_c = (const float*)d_in[11];
  const float* Wk_c = (const float*)d_in[12];
  const float* bk_c = (const float*)d_in[13];
  const float* Wv_c = (const float*)d_in[14];
  const float* bv_c = (const float*)d_in[15];
  const float* Wo_c = (const float*)d_in[16];
  const float* bo_c = (const float*)d_in[17];
  const float* W1   = (const float*)d_in[18];
  const float* b1   = (const float*)d_in[19];
  const float* W2   = (const float*)d_in[20];
  const float* b2   = (const float*)d_in[21];
  float* out = (float*)d_out;

  // ws layout (MB): 0-8 qs/as_; 8-40 ks,vs,u_attn (later h_spk over 8-40);
  // 40-48 s1; 48-56 WhT; 56-64 WmT; 64-72 Ah; 72-80 Am; 80-88 flags; 88 cnts.
  char* pool = (char*)d_ws;
  const size_t MB = 1024 * 1024;
  unsigned short* qs     = (unsigned short*)(pool + 0 * MB);
  unsigned short* ks     = (unsigned short*)(pool + 8 * MB);
  unsigned short* vs     = (unsigned short*)(pool + 16 * MB);
  float*          u_attn = (float*)(pool + 24 * MB);
  unsigned short* as_    = (unsigned short*)(pool + 0 * MB);
  unsigned short* h_spk  = (unsigned short*)(pool + 8 * MB);
  unsigned short* s1     = (unsigned short*)(pool + 40 * MB);
  unsigned short* WhT    = (unsigned short*)(pool + 48 * MB);
  unsigned short* WmT    = (unsigned short*)(pool + 56 * MB);
  unsigned short* Ahp    = (unsigned short*)(pool + 64 * MB);
  unsigned short* Amp    = (unsigned short*)(pool + 72 * MB);
  unsigned int*   flags  = (unsigned int*)(pool + 80 * MB);
  unsigned int*   cnts   = (unsigned int*)(pool + 88 * MB);

  // element offsets of each matrix inside WhT/WmT pools
  const size_t OQS = 0, OKS = 262144, OVS = 524288, OOS = 786432;
  const size_t OQC = 1048576, OKC = 1310720, OVC = 1572864, OOC = 1835008;
  const size_t OW1 = 2097152, OW2 = 3145728;

  const float ERR512 = 1.1f * 512.f * 5.96e-8f + 4.6e-5f;   // ~7.96e-5
  const float ERR2048 = 1.1f * 2048.f * 5.96e-8f + 4.6e-5f; // ~1.80e-4

  const unsigned short* NULS = nullptr;
  const float* NULF = nullptr;
  dim3 blk(256);
  int gLif = (BN * D_DIM) / 256;

  zero_k<<<1, 64, 0, stream>>>(cnts);
  wsplit_k<<<4096, blk, 0, stream>>>(Wq_s, Wk_s, Wv_s, Wo_s, Wq_c, Wk_c, Wv_c,
                                     Wo_c, W1, W2, WhT, WmT);

  // ---- Block 1: self-attention ----
  asplit_k<<<2048, blk, 0, stream>>>(x, NULS, Ahp, Amp);
  gemm_ns<<<dim3(24, 128), blk, 0, stream>>>(
      Ahp, Amp, WhT + OQS, WhT + OKS, WhT + OVS, WmT + OQS, WmT + OKS, WmT + OVS,
      bq_s, bk_s, bv_s, NULS, NULF, NULS, qs, ks, vs,
      cnts + 0, flags, 512, 512, 8, MODE_SPK, ERR512);
  fix_k<<<1024, blk, 0, stream>>>(x, NULS, Wq_s, Wk_s, Wv_s,
      bq_s, bk_s, bv_s, NULF, NULS, qs, ks, vs, cnts + 0, flags, 512, 512, MODE_SPK, 0);
  attn_k<<<128, blk, 0, stream>>>(qs, ks, vs, u_attn);
  lif_plane<<<gLif, blk, 0, stream>>>(u_attn, as_);
  gemm_ns<<<dim3(8, 128), blk, 0, stream>>>(
      as_, NULS, WhT + OOS, WhT + OOS, WhT + OOS, WmT + OOS, WmT + OOS, WmT + OOS,
      bo_s, bo_s, bo_s, NULS, NULF, NULS, s1, s1, s1,
      cnts + 1, flags, 512, 512, 8, MODE_SPK, ERR512);
  fix_k<<<1024, blk, 0, stream>>>(as_, NULS, Wo_s, Wo_s, Wo_s,
      bo_s, bo_s, bo_s, NULF, NULS, s1, s1, s1, cnts + 1, flags, 512, 512, MODE_SPK, 1);

  // ---- Block 2: cross-attention ----
  asplit_k<<<2048, blk, 0, stream>>>(x, s1, Ahp, Amp);
  gemm_ns<<<dim3(8, 128), blk, 0, stream>>>(
      Ahp, Amp, WhT + OQC, WhT + OQC, WhT + OQC, WmT + OQC, WmT + OQC, WmT + OQC,
      bq_c, bq_c, bq_c, NULS, NULF, NULS, qs, qs, qs,
      cnts + 2, flags, 512, 512, 8, MODE_SPK, ERR512);
  fix_k<<<1024, blk, 0, stream>>>(x, s1, Wq_c, Wq_c, Wq_c,
      bq_c, bq_c, bq_c, NULF, NULS, qs, qs, qs, cnts + 2, flags, 512, 512, MODE_SPK, 0);
  asplit_k<<<2048, blk, 0, stream>>>(enc, NULS, Ahp, Amp);
  gemm_ns<<<dim3(16, 128), blk, 0, stream>>>(
      Ahp, Amp, WhT + OKC, WhT + OVC, WhT + OVC, WmT + OKC, WmT + OVC, WmT + OVC,
      bk_c, bv_c, bv_c, NULS, NULF, NULS, ks, vs, vs,
      cnts + 3, flags, 512, 512, 8, MODE_SPK, ERR512);
  fix_k<<<1024, blk, 0, stream>>>(enc, NULS, Wk_c, Wv_c, Wv_c,
      bk_c, bv_c, bv_c, NULF, NULS, ks, vs, vs, cnts + 3, flags, 512, 512, MODE_SPK, 0);
  attn_k<<<128, blk, 0, stream>>>(qs, ks, vs, u_attn);
  lif_plane<<<gLif, blk, 0, stream>>>(u_attn, as_);
  gemm_ns<<<dim3(8, 128), blk, 0, stream>>>(
      as_, NULS, WhT + OOC, WhT + OOC, WhT + OOC, WmT + OOC, WmT + OOC, WmT + OOC,
      bo_c, bo_c, bo_c, s1, NULF, NULS, s1, s1, s1,
      cnts + 4, flags, 512, 512, 8, MODE_SPK_ADD, ERR512);
  fix_k<<<1024, blk, 0, stream>>>(as_, NULS, Wo_c, Wo_c, Wo_c,
      bo_c, bo_c, bo_c, NULF, NULS, s1, s1, s1, cnts + 4, flags, 512, 512, MODE_SPK_ADD, 1);

  // ---- Block 3: spiking MLP ----
  asplit_k<<<2048, blk, 0, stream>>>(x, s1, Ahp, Amp);
  gemm_ns<<<dim3(32, 128), blk, 0, stream>>>(
      Ahp, Amp, WhT + OW1, WhT + OW1, WhT + OW1, WmT + OW1, WmT + OW1, WmT + OW1,
      b1, b1, b1, NULS, NULF, NULS, h_spk, h_spk, h_spk,
      cnts + 5, flags, 2048, 512, 32, MODE_SPK, ERR512);
  fix_k<<<1024, blk, 0, stream>>>(x, s1, W1, W1, W1,
      b1, b1, b1, NULF, NULS, h_spk, h_spk, h_spk, cnts + 5, flags, 2048, 512, MODE_SPK, 0);
  gemm_ns<<<dim3(8, 128), blk, 0, stream>>>(
      h_spk, NULS, WhT + OW2, WhT + OW2, WhT + OW2, WmT + OW2, WmT + OW2, WmT + OW2,
      b2, b2, b2, NULS, x, s1, out, out, out,
      cnts + 6, flags, 512, 2048, 8, MODE_OUT, ERR2048);
  fix_k<<<1024, blk, 0, stream>>>(h_spk, NULS, W2, W2, W2,
      b2, b2, b2, x, s1, out, out, out, cnts + 6, flags, 512, 2048, MODE_OUT, 1);

  (void)in_sizes; (void)n_in; (void)out_size; (void)ws_size;
}